// Round 1
// baseline (3476.817 us; speedup 1.0000x reference)
//
#include <hip/hip_runtime.h>
#include <math.h>

constexpr int N    = 100000;
constexpr int E    = 1600000;
constexpr int DIN  = 256;
constexpr int D    = 128;
constexpr int L    = 4;
constexpr float EPS = 1e-5f;

// ---------------- CSR build ----------------

__global__ void k_count(const int* __restrict__ col, int* __restrict__ cnt) {
    int e = blockIdx.x * 256 + threadIdx.x;
    if (e < E) atomicAdd(&cnt[col[e]], 1);
}

__global__ void k_dis(const int* __restrict__ cnt, float* __restrict__ dis) {
    int n = blockIdx.x * 256 + threadIdx.x;
    if (n < N) dis[n] = rsqrtf((float)cnt[n] + 1.0f);   // +1 self-loop
}

// per-1024-chunk sums
__global__ void k_blocksum(const int* __restrict__ cnt, int* __restrict__ bsum) {
    __shared__ int s[256];
    int base = blockIdx.x * 1024;
    int t = threadIdx.x;
    int a = 0;
    for (int j = 0; j < 4; j++) {
        int idx = base + t * 4 + j;
        if (idx < N) a += cnt[idx];
    }
    s[t] = a; __syncthreads();
    for (int off = 128; off > 0; off >>= 1) {
        if (t < off) s[t] += s[t + off];
        __syncthreads();
    }
    if (t == 0) bsum[blockIdx.x] = s[0];
}

__global__ void k_scanbsum(int* bsum, int nb) {
    if (blockIdx.x == 0 && threadIdx.x == 0) {
        int acc = 0;
        for (int i = 0; i < nb; i++) { int v = bsum[i]; bsum[i] = acc; acc += v; }
    }
}

__global__ void k_offsets(const int* __restrict__ cnt, const int* __restrict__ bsum,
                          int* __restrict__ offs) {
    __shared__ int ls[256];
    int b = blockIdx.x, t = threadIdx.x;
    int base = b * 1024;
    int v[4]; int s = 0;
    for (int j = 0; j < 4; j++) {
        int idx = base + t * 4 + j;
        v[j] = (idx < N) ? cnt[idx] : 0;
        s += v[j];
    }
    ls[t] = s; __syncthreads();
    // Hillis-Steele inclusive scan
    for (int off = 1; off < 256; off <<= 1) {
        int x = (t >= off) ? ls[t - off] : 0;
        __syncthreads();
        ls[t] += x;
        __syncthreads();
    }
    int excl = ((t == 0) ? 0 : ls[t - 1]) + bsum[b];
    for (int j = 0; j < 4; j++) {
        int idx = base + t * 4 + j;
        if (idx < N) offs[idx] = excl;
        excl += v[j];
        if (idx == N - 1) offs[N] = excl;
    }
}

__global__ void k_scatter(const int* __restrict__ row, const int* __restrict__ col,
                          const float* __restrict__ dis, const int* __restrict__ offs,
                          int* __restrict__ cur, int* __restrict__ csr_src,
                          float* __restrict__ csr_val) {
    int e = blockIdx.x * 256 + threadIdx.x;
    if (e >= E) return;
    int c = col[e], r = row[e];
    int pos = offs[c] + atomicAdd(&cur[c], 1);
    csr_src[pos] = r;
    csr_val[pos] = dis[r] * dis[c];
}

// ---------------- dense / elementwise ----------------

// lin1_w [D][DIN] -> wt [DIN][D]
__global__ void k_wt(const float* __restrict__ w, float* __restrict__ wt) {
    int i = blockIdx.x * 256 + threadIdx.x;
    if (i < D * DIN) { int d = i / DIN, k = i % DIN; wt[k * D + d] = w[i]; }
}

// f0 = relu(x @ W^T + b); f <- f0 ; x0 <- 0.5*f0
__global__ void k_f0(const float* __restrict__ x, const float* __restrict__ wt,
                     const float* __restrict__ bias, float* __restrict__ f,
                     float* __restrict__ x0) {
    __shared__ float xs[2][DIN];
    int t = threadIdx.x;
    int n0 = blockIdx.x * 2;
    for (int j = t; j < 2 * DIN; j += 256) {
        int nn = n0 + (j >> 8);
        if (nn < N) xs[j >> 8][j & 255] = x[nn * DIN + (j & 255)];
    }
    __syncthreads();
    int node = n0 + (t >> 7), d = t & 127;
    if (node >= N) return;
    const float* xr = xs[t >> 7];
    float acc = bias[d];
    #pragma unroll 4
    for (int k = 0; k < DIN; k++) acc += xr[k] * wt[k * D + d];
    float r = fmaxf(acc, 0.f);
    f[node * D + d] = r;
    x0[node * D + d] = 0.5f * r;
}

// h = 0.5 * (A_hat @ f)
__global__ void k_agg(const float* __restrict__ f, const int* __restrict__ offs,
                      const int* __restrict__ csr_src, const float* __restrict__ csr_val,
                      const float* __restrict__ dis, float* __restrict__ h) {
    int t = threadIdx.x;
    int node = blockIdx.x * 2 + (t >> 7);
    if (node >= N) return;
    int d = t & 127;
    float sw = dis[node];
    float acc = f[node * D + d] * sw * sw;   // self loop
    int e1 = offs[node + 1];
    for (int e = offs[node]; e < e1; e++) {
        acc += f[csr_src[e] * D + d] * csr_val[e];
    }
    h[node * D + d] = 0.5f * acc;            // * (1 - ALPHA)
}

// out = (1-beta)*(h + x0) + beta*(h@w1 + x0@w2); write in place to h; partial LN stats
__global__ void k_combine(float* __restrict__ h, const float* __restrict__ x0,
                          const float* __restrict__ w1, const float* __restrict__ w2,
                          float beta, float* __restrict__ partials) {
    __shared__ float hs[2][D];
    __shared__ float xs[2][D];
    __shared__ float red[256];
    int t = threadIdx.x;
    int n0 = blockIdx.x * 2;
    for (int j = t; j < 2 * D; j += 256) {
        int nn = n0 + (j >> 7);
        if (nn < N) {
            hs[j >> 7][j & 127] = h[nn * D + (j & 127)];
            xs[j >> 7][j & 127] = x0[nn * D + (j & 127)];
        }
    }
    __syncthreads();
    int node = n0 + (t >> 7), d = t & 127;
    float res = 0.f;
    if (node < N) {
        const float* hr = hs[t >> 7];
        const float* xr = xs[t >> 7];
        float a1 = 0.f, a2 = 0.f;
        #pragma unroll 4
        for (int k = 0; k < D; k++) {
            a1 += hr[k] * w1[k * D + d];
            a2 += xr[k] * w2[k * D + d];
        }
        res = (1.f - beta) * (hr[d] + xr[d]) + beta * (a1 + a2);
        h[node * D + d] = res;
    }
    // block reduction: sum then sumsq
    red[t] = res; __syncthreads();
    for (int off = 128; off > 0; off >>= 1) { if (t < off) red[t] += red[t + off]; __syncthreads(); }
    if (t == 0) partials[blockIdx.x * 2] = red[0];
    __syncthreads();
    red[t] = res * res; __syncthreads();
    for (int off = 128; off > 0; off >>= 1) { if (t < off) red[t] += red[t + off]; __syncthreads(); }
    if (t == 0) partials[blockIdx.x * 2 + 1] = red[0];
}

__global__ void k_stats(const float* __restrict__ partials, int nb, float* __restrict__ stats) {
    __shared__ float s1[256], s2[256];
    int t = threadIdx.x;
    float a = 0, b = 0;
    for (int i = t; i < nb; i += 256) { a += partials[2 * i]; b += partials[2 * i + 1]; }
    s1[t] = a; s2[t] = b; __syncthreads();
    for (int off = 128; off > 0; off >>= 1) {
        if (t < off) { s1[t] += s1[t + off]; s2[t] += s2[t + off]; }
        __syncthreads();
    }
    if (t == 0) {
        const float inv_n = 1.0f / ((float)N * (float)D);
        float m = s1[0] * inv_n;
        float var = s2[0] * inv_n - m * m;
        var = fmaxf(var, 0.f);
        stats[0] = m;
        stats[1] = 1.0f / (sqrtf(var) + EPS);
    }
}

__global__ void k_ln_relu(const float* __restrict__ out, const float* __restrict__ stats,
                          const float* __restrict__ nw, const float* __restrict__ nb,
                          float* __restrict__ f) {
    int i = blockIdx.x * 256 + threadIdx.x;
    if (i >= N * D / 4) return;
    float m = stats[0], inv = stats[1];
    float4 v = ((const float4*)out)[i];
    int c = (i & 31) * 4;   // channel of first lane-elem: (i*4) % 128
    v.x = fmaxf((v.x - m) * inv * nw[c + 0] + nb[c + 0], 0.f);
    v.y = fmaxf((v.y - m) * inv * nw[c + 1] + nb[c + 1], 0.f);
    v.z = fmaxf((v.z - m) * inv * nw[c + 2] + nb[c + 2], 0.f);
    v.w = fmaxf((v.w - m) * inv * nw[c + 3] + nb[c + 3], 0.f);
    ((float4*)f)[i] = v;
}

// ---------------- launcher ----------------

extern "C" void kernel_launch(void* const* d_in, const int* in_sizes, int n_in,
                              void* d_out, int out_size, void* d_ws, size_t ws_size,
                              hipStream_t stream) {
    const float* x      = (const float*)d_in[0];
    const int*   ei     = (const int*)d_in[1];
    const float* lin1_w = (const float*)d_in[2];
    const float* lin1_b = (const float*)d_in[3];
    const float* w1     = (const float*)d_in[4];
    const float* w2     = (const float*)d_in[5];
    const float* nw     = (const float*)d_in[6];
    const float* nb     = (const float*)d_in[7];
    const int* row = ei;
    const int* col = ei + E;
    float* f = (float*)d_out;

    char* ws = (char*)d_ws;
    size_t off0 = 0;
    auto alloc = [&](size_t bytes) -> char* {
        char* p = ws + off0;
        off0 = (off0 + bytes + 255) & ~(size_t)255;
        return p;
    };
    float* x0       = (float*)alloc((size_t)N * D * 4);
    float* h        = (float*)alloc((size_t)N * D * 4);
    float* dis      = (float*)alloc((size_t)N * 4);
    int*   cnt      = (int*)  alloc((size_t)N * 4);
    int*   offs     = (int*)  alloc((size_t)(N + 1) * 4);
    int*   cur      = (int*)  alloc((size_t)N * 4);
    int*   bsum     = (int*)  alloc((size_t)((N + 1023) / 1024) * 4);
    int*   csr_src  = (int*)  alloc((size_t)E * 4);
    float* csr_val  = (float*)alloc((size_t)E * 4);
    float* partials = (float*)alloc((size_t)((N + 1) / 2) * 2 * 4);
    float* stats    = (float*)alloc(64);
    float* wt       = (float*)alloc((size_t)DIN * D * 4);

    hipMemsetAsync(cnt, 0, (size_t)N * 4, stream);
    hipMemsetAsync(cur, 0, (size_t)N * 4, stream);

    k_count<<<(E + 255) / 256, 256, 0, stream>>>(col, cnt);
    k_dis<<<(N + 255) / 256, 256, 0, stream>>>(cnt, dis);
    int nbk = (N + 1023) / 1024;
    k_blocksum<<<nbk, 256, 0, stream>>>(cnt, bsum);
    k_scanbsum<<<1, 64, 0, stream>>>(bsum, nbk);
    k_offsets<<<nbk, 256, 0, stream>>>(cnt, bsum, offs);
    k_scatter<<<(E + 255) / 256, 256, 0, stream>>>(row, col, dis, offs, cur, csr_src, csr_val);

    k_wt<<<(D * DIN + 255) / 256, 256, 0, stream>>>(lin1_w, wt);
    int nblk2 = (N + 1) / 2;
    k_f0<<<nblk2, 256, 0, stream>>>(x, wt, lin1_b, f, x0);

    for (int i = 0; i < L; i++) {
        float beta = logf(1.0f / (float)(i + 1) + 1.0f);
        k_agg<<<nblk2, 256, 0, stream>>>(f, offs, csr_src, csr_val, dis, h);
        k_combine<<<nblk2, 256, 0, stream>>>(h, x0, w1 + (size_t)i * D * D,
                                             w2 + (size_t)i * D * D, beta, partials);
        k_stats<<<1, 256, 0, stream>>>(partials, nblk2, stats);
        k_ln_relu<<<(N * D / 4 + 255) / 256, 256, 0, stream>>>(h, stats, nw, nb, f);
    }
}

// Round 2
// 709.421 us; speedup vs baseline: 4.9009x; 4.9009x over previous
//
#include <hip/hip_runtime.h>
#include <math.h>

constexpr int N    = 100000;
constexpr int E    = 1600000;
constexpr int DIN  = 256;
constexpr int D    = 128;
constexpr int L    = 4;
constexpr float EPS = 1e-5f;

typedef __attribute__((ext_vector_type(8))) short bf16x8;
typedef __attribute__((ext_vector_type(4))) float f32x4;

__device__ inline ushort f2b(float f) {
    uint u = __float_as_uint(f);
    uint r = u + 0x7fffu + ((u >> 16) & 1u);
    return (ushort)(r >> 16);
}
__device__ inline float b2f(ushort b) { return __uint_as_float(((uint)b) << 16); }

// ---------------- CSR build ----------------

__global__ void k_count(const int* __restrict__ col, int* __restrict__ cnt) {
    int e = blockIdx.x * 256 + threadIdx.x;
    if (e < E) atomicAdd(&cnt[col[e]], 1);
}

__global__ void k_dis(const int* __restrict__ cnt, float* __restrict__ dis) {
    int n = blockIdx.x * 256 + threadIdx.x;
    if (n < N) dis[n] = rsqrtf((float)cnt[n] + 1.0f);   // +1 self-loop
}

__global__ void k_blocksum(const int* __restrict__ cnt, int* __restrict__ bsum) {
    __shared__ int s[256];
    int base = blockIdx.x * 1024;
    int t = threadIdx.x;
    int a = 0;
    for (int j = 0; j < 4; j++) {
        int idx = base + t * 4 + j;
        if (idx < N) a += cnt[idx];
    }
    s[t] = a; __syncthreads();
    for (int off = 128; off > 0; off >>= 1) {
        if (t < off) s[t] += s[t + off];
        __syncthreads();
    }
    if (t == 0) bsum[blockIdx.x] = s[0];
}

__global__ void k_scanbsum(int* bsum, int nb) {
    if (blockIdx.x == 0 && threadIdx.x == 0) {
        int acc = 0;
        for (int i = 0; i < nb; i++) { int v = bsum[i]; bsum[i] = acc; acc += v; }
    }
}

__global__ void k_offsets(const int* __restrict__ cnt, const int* __restrict__ bsum,
                          int* __restrict__ offs) {
    __shared__ int ls[256];
    int b = blockIdx.x, t = threadIdx.x;
    int base = b * 1024;
    int v[4]; int s = 0;
    for (int j = 0; j < 4; j++) {
        int idx = base + t * 4 + j;
        v[j] = (idx < N) ? cnt[idx] : 0;
        s += v[j];
    }
    ls[t] = s; __syncthreads();
    for (int off = 1; off < 256; off <<= 1) {
        int x = (t >= off) ? ls[t - off] : 0;
        __syncthreads();
        ls[t] += x;
        __syncthreads();
    }
    int excl = ((t == 0) ? 0 : ls[t - 1]) + bsum[b];
    for (int j = 0; j < 4; j++) {
        int idx = base + t * 4 + j;
        if (idx < N) offs[idx] = excl;
        excl += v[j];
        if (idx == N - 1) offs[N] = excl;
    }
}

__global__ void k_scatter(const int* __restrict__ row, const int* __restrict__ col,
                          const float* __restrict__ dis, const int* __restrict__ offs,
                          int* __restrict__ cur, int* __restrict__ csr_src,
                          float* __restrict__ csr_val) {
    int e = blockIdx.x * 256 + threadIdx.x;
    if (e >= E) return;
    int c = col[e], r = row[e];
    int pos = offs[c] + atomicAdd(&cur[c], 1);
    csr_src[pos] = r;
    csr_val[pos] = dis[r] * dis[c];
}

// ---------------- weight prep (bf16, col-major-in-k, identity folded) ----------------

// wb0[d*256+k] = bf16(lin1_w[d][k])                       (f0 B matrix)
// wbc[l][d*256+k] = bf16(beta*w[k][d] + (k==d)(1-beta))   (combine B matrix, K=256 = [w1;w2])
__global__ void k_prep_w(const float* __restrict__ lin1_w, const float* __restrict__ w1,
                         const float* __restrict__ w2, float4 betas,
                         ushort* __restrict__ wb0, ushort* __restrict__ wbc) {
    int i = blockIdx.x * 256 + threadIdx.x;
    if (i < D * DIN) wb0[i] = f2b(lin1_w[i]);
    if (i < L * D * 256) {
        int l = i >> 15, r = i & 32767, d = r >> 8, k = r & 255;
        float beta = (l == 0) ? betas.x : (l == 1) ? betas.y : (l == 2) ? betas.z : betas.w;
        float v;
        if (k < 128) v = beta * w1[l * 16384 + k * 128 + d] + ((k == d) ? (1.f - beta) : 0.f);
        else { int kk = k - 128; v = beta * w2[l * 16384 + kk * 128 + d] + ((kk == d) ? (1.f - beta) : 0.f); }
        wbc[l * 32768 + d * 256 + k] = f2b(v);
    }
}

// ---------------- MFMA GEMM kernels (BM=128, BN=128, K=256) ----------------
// LDS layout: row-major [128][256] bf16, byte-within-row XOR-swizzled by ((row&15)<<4).

#define LSWZ(rw, byt) ((rw) * 512 + ((byt) ^ (((rw) & 15) << 4)))

// f = relu(x @ lin1_w^T + b); f_bf <- bf16(f); x0_bf <- bf16(0.5f*f)
__global__ __launch_bounds__(256) void k_f0_mfma(const float* __restrict__ x,
        const ushort* __restrict__ wb, const float* __restrict__ bias,
        ushort* __restrict__ f_bf, ushort* __restrict__ x0_bf) {
    __shared__ ushort Al[128 * 256];
    __shared__ ushort Bl[128 * 256];
    int t = threadIdx.x;
    int row0 = blockIdx.x * 128;

    // stage B (bf16 col-major [128 cols][256 k], contiguous)
    #pragma unroll
    for (int i = 0; i < 16; i++) {
        int c = i * 256 + t;
        int cl = c >> 5, sub = c & 31;
        uint4 v = ((const uint4*)wb)[c];
        *(uint4*)((char*)Bl + LSWZ(cl, sub * 16)) = v;
    }
    // stage A: fp32 x -> bf16
    #pragma unroll
    for (int i = 0; i < 16; i++) {
        int c = i * 256 + t;
        int rw = c >> 5, sub = c & 31;
        int gr = row0 + rw;
        uint4 p = {0, 0, 0, 0};
        if (gr < N) {
            const float4* src = (const float4*)(x + (size_t)gr * 256 + sub * 8);
            float4 lo = src[0], hi = src[1];
            p.x = (uint)f2b(lo.x) | ((uint)f2b(lo.y) << 16);
            p.y = (uint)f2b(lo.z) | ((uint)f2b(lo.w) << 16);
            p.z = (uint)f2b(hi.x) | ((uint)f2b(hi.y) << 16);
            p.w = (uint)f2b(hi.z) | ((uint)f2b(hi.w) << 16);
        }
        *(uint4*)((char*)Al + LSWZ(rw, sub * 16)) = p;
    }
    __syncthreads();

    int wv = t >> 6, lane = t & 63;
    int l16 = lane & 15, g16 = lane >> 4;
    f32x4 acc[2][8];
    #pragma unroll
    for (int m = 0; m < 2; m++)
        #pragma unroll
        for (int n = 0; n < 8; n++) acc[m][n] = f32x4{0.f, 0.f, 0.f, 0.f};

    #pragma unroll
    for (int ks = 0; ks < 8; ks++) {
        int kb = ks * 64 + g16 * 16;
        bf16x8 a[2], b[8];
        #pragma unroll
        for (int m = 0; m < 2; m++) {
            int r = wv * 32 + m * 16 + l16;
            a[m] = *(const bf16x8*)((const char*)Al + LSWZ(r, kb));
        }
        #pragma unroll
        for (int n = 0; n < 8; n++) {
            int cl = n * 16 + l16;
            b[n] = *(const bf16x8*)((const char*)Bl + LSWZ(cl, kb));
        }
        #pragma unroll
        for (int m = 0; m < 2; m++)
            #pragma unroll
            for (int n = 0; n < 8; n++)
                acc[m][n] = __builtin_amdgcn_mfma_f32_16x16x32_bf16(a[m], b[n], acc[m][n], 0, 0, 0);
    }

    float bc[8];
    #pragma unroll
    for (int n = 0; n < 8; n++) bc[n] = bias[n * 16 + l16];
    #pragma unroll
    for (int m = 0; m < 2; m++)
        #pragma unroll
        for (int j = 0; j < 4; j++) {
            int gr = row0 + wv * 32 + m * 16 + g16 * 4 + j;
            if (gr >= N) continue;
            #pragma unroll
            for (int n = 0; n < 8; n++) {
                float r = fmaxf(acc[m][n][j] + bc[n], 0.f);
                size_t o = (size_t)gr * 128 + n * 16 + l16;
                f_bf[o] = f2b(r);
                x0_bf[o] = f2b(0.5f * r);
            }
        }
}

// out = [h|x0] @ wbc_l ; writes bf16(out) in-place into h_bf; block LN partial stats
__global__ __launch_bounds__(256) void k_combine_mfma(ushort* __restrict__ h_bf,
        const ushort* __restrict__ x0_bf, const ushort* __restrict__ wb,
        float* __restrict__ partials) {
    __shared__ ushort Al[128 * 256];
    __shared__ ushort Bl[128 * 256];
    __shared__ float red1[256];
    __shared__ float red2[256];
    int t = threadIdx.x;
    int row0 = blockIdx.x * 128;

    #pragma unroll
    for (int i = 0; i < 16; i++) {
        int c = i * 256 + t;
        int cl = c >> 5, sub = c & 31;
        uint4 v = ((const uint4*)wb)[c];
        *(uint4*)((char*)Bl + LSWZ(cl, sub * 16)) = v;
    }
    #pragma unroll
    for (int i = 0; i < 16; i++) {
        int c = i * 256 + t;
        int rw = c >> 5, sub = c & 31;
        int gr = row0 + rw;
        uint4 v = {0, 0, 0, 0};
        if (gr < N) {
            const ushort* src = (sub < 16 ? h_bf : x0_bf) + (size_t)gr * 128;
            v = ((const uint4*)src)[sub & 15];
        }
        *(uint4*)((char*)Al + LSWZ(rw, sub * 16)) = v;
    }
    __syncthreads();

    int wv = t >> 6, lane = t & 63;
    int l16 = lane & 15, g16 = lane >> 4;
    f32x4 acc[2][8];
    #pragma unroll
    for (int m = 0; m < 2; m++)
        #pragma unroll
        for (int n = 0; n < 8; n++) acc[m][n] = f32x4{0.f, 0.f, 0.f, 0.f};

    #pragma unroll
    for (int ks = 0; ks < 8; ks++) {
        int kb = ks * 64 + g16 * 16;
        bf16x8 a[2], b[8];
        #pragma unroll
        for (int m = 0; m < 2; m++) {
            int r = wv * 32 + m * 16 + l16;
            a[m] = *(const bf16x8*)((const char*)Al + LSWZ(r, kb));
        }
        #pragma unroll
        for (int n = 0; n < 8; n++) {
            int cl = n * 16 + l16;
            b[n] = *(const bf16x8*)((const char*)Bl + LSWZ(cl, kb));
        }
        #pragma unroll
        for (int m = 0; m < 2; m++)
            #pragma unroll
            for (int n = 0; n < 8; n++)
                acc[m][n] = __builtin_amdgcn_mfma_f32_16x16x32_bf16(a[m], b[n], acc[m][n], 0, 0, 0);
    }

    // stats over fp32 acc (OOB rows are exactly 0 -> contribute nothing)
    float sum = 0.f, sq = 0.f;
    #pragma unroll
    for (int m = 0; m < 2; m++)
        #pragma unroll
        for (int n = 0; n < 8; n++)
            #pragma unroll
            for (int j = 0; j < 4; j++) { float v = acc[m][n][j]; sum += v; sq += v * v; }

    // store out (bf16) in place
    #pragma unroll
    for (int m = 0; m < 2; m++)
        #pragma unroll
        for (int j = 0; j < 4; j++) {
            int gr = row0 + wv * 32 + m * 16 + g16 * 4 + j;
            if (gr >= N) continue;
            #pragma unroll
            for (int n = 0; n < 8; n++)
                h_bf[(size_t)gr * 128 + n * 16 + l16] = f2b(acc[m][n][j]);
        }

    red1[t] = sum; red2[t] = sq; __syncthreads();
    for (int off = 128; off > 0; off >>= 1) {
        if (t < off) { red1[t] += red1[t + off]; red2[t] += red2[t + off]; }
        __syncthreads();
    }
    if (t == 0) { partials[blockIdx.x * 2] = red1[0]; partials[blockIdx.x * 2 + 1] = red2[0]; }
}

// ---------------- aggregation: wave per node, bf16 rows ----------------

__global__ void k_agg(const ushort* __restrict__ f_bf, const int* __restrict__ offs,
                      const int* __restrict__ csr_src, const float* __restrict__ csr_val,
                      const float* __restrict__ dis, ushort* __restrict__ h_bf) {
    int node = blockIdx.x * 4 + (threadIdx.x >> 6);
    if (node >= N) return;
    int lane = threadIdx.x & 63;
    const uint* fu = (const uint*)f_bf;
    float dv = dis[node];
    uint sf = fu[(size_t)node * 64 + lane];
    float a0 = b2f((ushort)(sf & 0xffff)) * dv * dv;
    float a1 = b2f((ushort)(sf >> 16)) * dv * dv;
    int e = offs[node], end = offs[node + 1];
    for (; e + 4 <= end; e += 4) {
        int s0 = csr_src[e], s1 = csr_src[e + 1], s2 = csr_src[e + 2], s3 = csr_src[e + 3];
        float v0 = csr_val[e], v1 = csr_val[e + 1], v2 = csr_val[e + 2], v3 = csr_val[e + 3];
        uint r0 = fu[(size_t)s0 * 64 + lane];
        uint r1 = fu[(size_t)s1 * 64 + lane];
        uint r2 = fu[(size_t)s2 * 64 + lane];
        uint r3 = fu[(size_t)s3 * 64 + lane];
        a0 += v0 * b2f((ushort)(r0 & 0xffff)) + v1 * b2f((ushort)(r1 & 0xffff))
            + v2 * b2f((ushort)(r2 & 0xffff)) + v3 * b2f((ushort)(r3 & 0xffff));
        a1 += v0 * b2f((ushort)(r0 >> 16)) + v1 * b2f((ushort)(r1 >> 16))
            + v2 * b2f((ushort)(r2 >> 16)) + v3 * b2f((ushort)(r3 >> 16));
    }
    for (; e < end; e++) {
        int s = csr_src[e]; float v = csr_val[e];
        uint r = fu[(size_t)s * 64 + lane];
        a0 += v * b2f((ushort)(r & 0xffff));
        a1 += v * b2f((ushort)(r >> 16));
    }
    ((uint*)h_bf)[(size_t)node * 64 + lane] =
        (uint)f2b(0.5f * a0) | ((uint)f2b(0.5f * a1) << 16);
}

// ---------------- LN finalize ----------------

__global__ void k_stats(const float* __restrict__ partials, int nb, float* __restrict__ stats) {
    __shared__ float s1[256], s2[256];
    int t = threadIdx.x;
    float a = 0, b = 0;
    for (int i = t; i < nb; i += 256) { a += partials[2 * i]; b += partials[2 * i + 1]; }
    s1[t] = a; s2[t] = b; __syncthreads();
    for (int off = 128; off > 0; off >>= 1) {
        if (t < off) { s1[t] += s1[t + off]; s2[t] += s2[t + off]; }
        __syncthreads();
    }
    if (t == 0) {
        const float inv_n = 1.0f / ((float)N * (float)D);
        float m = s1[0] * inv_n;
        float var = s2[0] * inv_n - m * m;
        var = fmaxf(var, 0.f);
        stats[0] = m;
        stats[1] = 1.0f / (sqrtf(var) + EPS);
    }
}

template <int LAST>
__global__ void k_ln_relu(const ushort* __restrict__ ob, const float* __restrict__ stats,
                          const float* __restrict__ nw, const float* __restrict__ nb,
                          ushort* __restrict__ f_bf, float* __restrict__ fout) {
    int i = blockIdx.x * 256 + threadIdx.x;   // uint4 index: 8 bf16
    if (i >= N * 16) return;
    float m = stats[0], inv = stats[1];
    uint4 v = ((const uint4*)ob)[i];
    int c = (i & 15) * 8;
    uint vv[4] = {v.x, v.y, v.z, v.w};
    float r[8];
    #pragma unroll
    for (int q = 0; q < 4; q++) {
        float lo = b2f((ushort)(vv[q] & 0xffff));
        float hi = b2f((ushort)(vv[q] >> 16));
        r[2 * q]     = fmaxf((lo - m) * inv * nw[c + 2 * q]     + nb[c + 2 * q], 0.f);
        r[2 * q + 1] = fmaxf((hi - m) * inv * nw[c + 2 * q + 1] + nb[c + 2 * q + 1], 0.f);
    }
    if (LAST) {
        float4 o0 = {r[0], r[1], r[2], r[3]};
        float4 o1 = {r[4], r[5], r[6], r[7]};
        ((float4*)fout)[2 * i] = o0;
        ((float4*)fout)[2 * i + 1] = o1;
    } else {
        uint4 o;
        o.x = (uint)f2b(r[0]) | ((uint)f2b(r[1]) << 16);
        o.y = (uint)f2b(r[2]) | ((uint)f2b(r[3]) << 16);
        o.z = (uint)f2b(r[4]) | ((uint)f2b(r[5]) << 16);
        o.w = (uint)f2b(r[6]) | ((uint)f2b(r[7]) << 16);
        ((uint4*)f_bf)[i] = o;
    }
}

// ---------------- launcher ----------------

extern "C" void kernel_launch(void* const* d_in, const int* in_sizes, int n_in,
                              void* d_out, int out_size, void* d_ws, size_t ws_size,
                              hipStream_t stream) {
    const float* x      = (const float*)d_in[0];
    const int*   ei     = (const int*)d_in[1];
    const float* lin1_w = (const float*)d_in[2];
    const float* lin1_b = (const float*)d_in[3];
    const float* w1     = (const float*)d_in[4];
    const float* w2     = (const float*)d_in[5];
    const float* nw     = (const float*)d_in[6];
    const float* nb     = (const float*)d_in[7];
    const int* row = ei;
    const int* col = ei + E;
    float* fout = (float*)d_out;

    char* ws = (char*)d_ws;
    size_t off0 = 0;
    auto alloc = [&](size_t bytes) -> char* {
        char* p = ws + off0;
        off0 = (off0 + bytes + 255) & ~(size_t)255;
        return p;
    };
    ushort* f_bf    = (ushort*)alloc((size_t)N * D * 2);
    ushort* x0_bf   = (ushort*)alloc((size_t)N * D * 2);
    ushort* h_bf    = (ushort*)alloc((size_t)N * D * 2);
    float*  dis     = (float*) alloc((size_t)N * 4);
    int*    cnt     = (int*)   alloc((size_t)N * 4);
    int*    offs    = (int*)   alloc((size_t)(N + 1) * 4);
    int*    cur     = (int*)   alloc((size_t)N * 4);
    int*    bsum    = (int*)   alloc((size_t)((N + 1023) / 1024) * 4);
    int*    csr_src = (int*)   alloc((size_t)E * 4);
    float*  csr_val = (float*) alloc((size_t)E * 4);
    float*  partials= (float*) alloc((size_t)1024 * 2 * 4);
    float*  stats   = (float*) alloc(64);
    ushort* wb0     = (ushort*)alloc((size_t)D * DIN * 2);
    ushort* wbc     = (ushort*)alloc((size_t)L * D * 256 * 2);

    hipMemsetAsync(cnt, 0, (size_t)N * 4, stream);
    hipMemsetAsync(cur, 0, (size_t)N * 4, stream);

    // CSR build
    k_count<<<(E + 255) / 256, 256, 0, stream>>>(col, cnt);
    k_dis<<<(N + 255) / 256, 256, 0, stream>>>(cnt, dis);
    int nbk = (N + 1023) / 1024;
    k_blocksum<<<nbk, 256, 0, stream>>>(cnt, bsum);
    k_scanbsum<<<1, 64, 0, stream>>>(bsum, nbk);
    k_offsets<<<nbk, 256, 0, stream>>>(cnt, bsum, offs);
    k_scatter<<<(E + 255) / 256, 256, 0, stream>>>(row, col, dis, offs, cur, csr_src, csr_val);

    // weight prep
    float4 betas;
    betas.x = logf(1.0f / 1.0f + 1.0f);
    betas.y = logf(1.0f / 2.0f + 1.0f);
    betas.z = logf(1.0f / 3.0f + 1.0f);
    betas.w = logf(1.0f / 4.0f + 1.0f);
    k_prep_w<<<(L * D * 256 + 255) / 256, 256, 0, stream>>>(lin1_w, w1, w2, betas, wb0, wbc);

    int GB = (N + 127) / 128;   // 782
    k_f0_mfma<<<GB, 256, 0, stream>>>(x, wb0, lin1_b, f_bf, x0_bf);

    for (int i = 0; i < L; i++) {
        k_agg<<<(N + 3) / 4, 256, 0, stream>>>(f_bf, offs, csr_src, csr_val, dis, h_bf);
        k_combine_mfma<<<GB, 256, 0, stream>>>(h_bf, x0_bf, wbc + (size_t)i * D * 256, partials);
        k_stats<<<1, 256, 0, stream>>>(partials, GB, stats);
        if (i < L - 1)
            k_ln_relu<0><<<(N * 16 + 255) / 256, 256, 0, stream>>>(h_bf, stats, nw, nb, f_bf, fout);
        else
            k_ln_relu<1><<<(N * 16 + 255) / 256, 256, 0, stream>>>(h_bf, stats, nw, nb, f_bf, fout);
    }
}